// Round 2
// baseline (494.644 us; speedup 1.0000x reference)
//
#include <hip/hip_runtime.h>

#define EPS 1e-5f

typedef __attribute__((ext_vector_type(8))) short short8;
typedef __attribute__((ext_vector_type(4))) float f32x4;

// ---- ws layout ----
// shorts [0, 131072)      : shW frags, idx = (kq*256 + n)*8 + j, k = kq*8+j (BN0 scale folded)
// shorts [131072, 180224) : stW frags, idx = 131072 + s*16384 + (kq*128 + n')*8 + j,
//                           n = n' (<64) or n'+64
// floats (on d_ws as float*):
#define C1_OFF   90112
#define C2_OFF   90368
#define STC1_OFF 90624
#define STC2_OFF 91392

// HW bf16 conversion path (RNE, identical rounding to manual bit-twiddle).
__device__ inline unsigned short f2bf(float f) {
  return __builtin_bit_cast(unsigned short, (__bf16)f);
}

__device__ inline short8 cvt8(f32x4 a, f32x4 b) {
  short8 r;
  r[0] = (short)f2bf(a[0]); r[1] = (short)f2bf(a[1]);
  r[2] = (short)f2bf(a[2]); r[3] = (short)f2bf(a[3]);
  r[4] = (short)f2bf(b[0]); r[5] = (short)f2bf(b[1]);
  r[6] = (short)f2bf(b[2]); r[7] = (short)f2bf(b[3]);
  return r;
}

// ---------------- merged prep kernel ----------------
// blocks [0,88)   : weight-fragment repack (coalesced reads, 16B frag writes)
// blocks [88,344) : one block per output col n — folded BN0 bias reduction + BN consts
__global__ void prep_all(const float* __restrict__ shW, const float* __restrict__ stW,
                         const float* __restrict__ bn0_g, const float* __restrict__ bn0_b,
                         const float* __restrict__ bn0_m, const float* __restrict__ bn0_v,
                         const float* __restrict__ sh_g, const float* __restrict__ sh_b,
                         const float* __restrict__ sh_m, const float* __restrict__ sh_v,
                         const float* __restrict__ st_g, const float* __restrict__ st_b,
                         const float* __restrict__ st_m, const float* __restrict__ st_v,
                         unsigned short* __restrict__ ws, float* __restrict__ wsf) {
  if (blockIdx.x < 88) {
    int t = blockIdx.x * 256 + threadIdx.x;
    if (t < 16384) {
      int kq = t >> 8, n = t & 255;
      short8 o;
#pragma unroll
      for (int j = 0; j < 8; ++j) {
        int k = kq * 8 + j;
        float scale = bn0_g[k] * rsqrtf(bn0_v[k] + EPS);
        o[j] = (short)f2bf(shW[k * 256 + n] * scale);
      }
      *(short8*)&ws[t * 8] = o;
    } else if (t < 16384 + 6144) {
      int r = t - 16384;
      int s = r >> 11, rem = r & 2047;
      int kq = rem >> 7, np = rem & 127;
      int n = np < 64 ? np : np + 64;
      short8 o;
#pragma unroll
      for (int j = 0; j < 8; ++j) o[j] = (short)f2bf(stW[(s * 128 + kq * 8 + j) * 256 + n]);
      *(short8*)&ws[131072 + r * 8] = o;
    }
    return;
  }

  const int n = blockIdx.x - 88, t = threadIdx.x;
  float part = 0.f;
#pragma unroll
  for (int kk = 0; kk < 2; ++kk) {
    int k = t + kk * 256;
    float sc = bn0_g[k] * rsqrtf(bn0_v[k] + EPS);
    part += (bn0_b[k] - bn0_m[k] * sc) * shW[k * 256 + n];
  }
#pragma unroll
  for (int m = 1; m < 64; m <<= 1) part += __shfl_xor(part, m);
  __shared__ float wsum[4];
  if ((t & 63) == 0) wsum[t >> 6] = part;
  __syncthreads();
  if (t == 0) {
    float bias = wsum[0] + wsum[1] + wsum[2] + wsum[3];
    float c1 = sh_g[n] * rsqrtf(sh_v[n] + EPS);
    wsf[C1_OFF + n] = c1;
    wsf[C2_OFF + n] = (bias - sh_m[n]) * c1 + sh_b[n];
#pragma unroll
    for (int s = 0; s < 3; ++s) {
      float a = st_g[s * 256 + n] * rsqrtf(st_v[s * 256 + n] + EPS);
      wsf[STC1_OFF + s * 256 + n] = a;
      wsf[STC2_OFF + s * 256 + n] = st_b[s * 256 + n] - st_m[s * 256 + n] * a;
    }
  }
}

// ---------------- main fused kernel ----------------
// 4096 blocks x 256 threads, 32 rows/block. Halved per-wave tile (32 rows x
// 32val+32gate cols) keeps total VGPR+AGPR under the 128-reg occupancy cliff
// -> 4 waves/SIMD instead of 2 (latency-bound fix). B-frags load straight from
// ws (frag order -> coalesced dwordx4). GLU fully in registers, 2 barriers.
__global__ __launch_bounds__(256, 4) void tabnet_main(
    const float* __restrict__ x, const unsigned short* __restrict__ wsu,
    const float* __restrict__ wsf, const float* __restrict__ fW,
    const float* __restrict__ fb, float* __restrict__ out) {

  __shared__ __align__(16) unsigned short lds_sh[16 * 32 * 8];  // 8 KB, sh A-frags
  __shared__ float lds_red[4 * 32 * 2];                         // 1 KB

  const int tid = threadIdx.x;
  const int wave = tid >> 6, lane = tid & 63;
  const int q = lane >> 4, l15 = lane & 15;
  const long row0 = (long)blockIdx.x * 32;

  // B column per nt: nt 0,1 = value cols, nt 2,3 = gate cols (+128)
  int ncol[4];
#pragma unroll
  for (int nt = 0; nt < 4; ++nt)
    ncol[nt] = wave * 32 + (nt & 1) * 16 + (nt >> 1) * 128 + l15;

  const float* xrow = x + (row0 + l15) * 512 + q * 8;

  f32x4 acc[2][4];
#pragma unroll
  for (int a = 0; a < 2; ++a)
#pragma unroll
    for (int b = 0; b < 4; ++b) acc[a][b] = (f32x4)0.f;

  // ---- Phase 1: K=512 as 16 steps of 32; x pipelined 1 step ahead ----
  f32x4 xa[2], xb[2];
#pragma unroll
  for (int mt = 0; mt < 2; ++mt) {
    const float* p = xrow + mt * 8192;
    xa[mt] = *(const f32x4*)p;
    xb[mt] = *(const f32x4*)(p + 4);
  }
  for (int st = 0; st < 16; ++st) {
    // issue B loads for this step (latency hidden behind the x wait below)
    short8 bcur[4];
#pragma unroll
    for (int nt = 0; nt < 4; ++nt)
      bcur[nt] = *(const short8*)&wsu[((st * 4 + q) * 256 + ncol[nt]) * 8];
    // convert current x (waits on x loads issued last step)
    short8 af[2];
#pragma unroll
    for (int mt = 0; mt < 2; ++mt) af[mt] = cvt8(xa[mt], xb[mt]);
    // prefetch next step's x
    if (st < 15) {
#pragma unroll
      for (int mt = 0; mt < 2; ++mt) {
        const float* p = xrow + mt * 8192 + (st + 1) * 32;
        xa[mt] = *(const f32x4*)p;
        xb[mt] = *(const f32x4*)(p + 4);
      }
    }
#pragma unroll
    for (int nt = 0; nt < 4; ++nt)
#pragma unroll
      for (int mt = 0; mt < 2; ++mt)
        acc[mt][nt] =
            __builtin_amdgcn_mfma_f32_16x16x32_bf16(af[mt], bcur[nt], acc[mt][nt], 0, 0, 0);
  }

  // ---- Phase-1 epilogue: BN + GLU in registers -> lds_sh (A-frag layout) ----
#pragma unroll
  for (int nt = 0; nt < 2; ++nt) {
    const int c = wave * 32 + nt * 16 + l15;
    const float v1 = wsf[C1_OFF + c], v2 = wsf[C2_OFF + c];
    const float g1 = wsf[C1_OFF + c + 128], g2 = wsf[C2_OFF + c + 128];
#pragma unroll
    for (int mt = 0; mt < 2; ++mt)
#pragma unroll
      for (int r = 0; r < 4; ++r) {
        float y1 = acc[mt][nt][r] * v1 + v2;
        float y2 = acc[mt][nt + 2][r] * g1 + g2;
        float sg = __builtin_amdgcn_rcpf(1.f + __expf(-y2));
        int row = 16 * mt + 4 * q + r;
        lds_sh[((c >> 3) * 32 + row) * 8 + (c & 7)] = f2bf(y1 * sg);
      }
  }
  __syncthreads();

  // ---- Phase 2: 3 steps, K=128; A from lds_sh, B direct from global; GLU in regs ----
  float agg[8];
#pragma unroll
  for (int i = 0; i < 8; ++i) agg[i] = 0.f;

  for (int s = 0; s < 3; ++s) {
    const unsigned short* wb = wsu + 131072 + s * 16384;
    short8 bs[4][2];
#pragma unroll
    for (int ks = 0; ks < 4; ++ks) {
      int kq = ks * 4 + q;
      bs[ks][0] = *(const short8*)&wb[(kq * 128 + wave * 16 + l15) * 8];
      bs[ks][1] = *(const short8*)&wb[(kq * 128 + 64 + wave * 16 + l15) * 8];
    }
    f32x4 acc2[2][2];
#pragma unroll
    for (int a = 0; a < 2; ++a)
#pragma unroll
      for (int b = 0; b < 2; ++b) acc2[a][b] = (f32x4)0.f;
#pragma unroll
    for (int ks = 0; ks < 4; ++ks) {
      int kq = ks * 4 + q;
      short8 af[2];
#pragma unroll
      for (int mt = 0; mt < 2; ++mt)
        af[mt] = *(const short8*)&lds_sh[(kq * 32 + 16 * mt + l15) * 8];
#pragma unroll
      for (int nt = 0; nt < 2; ++nt)
#pragma unroll
        for (int mt = 0; mt < 2; ++mt)
          acc2[mt][nt] =
              __builtin_amdgcn_mfma_f32_16x16x32_bf16(af[mt], bs[ks][nt], acc2[mt][nt], 0, 0, 0);
    }
    const int n1 = wave * 16 + l15, n2 = 128 + wave * 16 + l15;
    const float a1 = wsf[STC1_OFF + s * 256 + n1], b1 = wsf[STC2_OFF + s * 256 + n1];
    const float a2 = wsf[STC1_OFF + s * 256 + n2], b2 = wsf[STC2_OFF + s * 256 + n2];
#pragma unroll
    for (int mt = 0; mt < 2; ++mt)
#pragma unroll
      for (int r = 0; r < 4; ++r) {
        float y1 = acc2[mt][0][r] * a1 + b1;
        float y2 = acc2[mt][1][r] * a2 + b2;
        agg[mt * 4 + r] += y1 * __builtin_amdgcn_rcpf(1.f + __expf(-y2));
      }
  }

  // ---- Final: out = agg @ fW + fb (shfl reduce over the 16 cols per wave) ----
  {
    const int c = wave * 16 + l15;
    const float w0 = fW[c * 2], w1 = fW[c * 2 + 1];
#pragma unroll
    for (int mt = 0; mt < 2; ++mt)
#pragma unroll
      for (int r = 0; r < 4; ++r) {
        float p0 = agg[mt * 4 + r] * w0;
        float p1 = agg[mt * 4 + r] * w1;
#pragma unroll
        for (int m = 1; m < 16; m <<= 1) {
          p0 += __shfl_xor(p0, m);
          p1 += __shfl_xor(p1, m);
        }
        if (l15 == 0) {
          int row = 16 * mt + 4 * q + r;
          lds_red[(wave * 32 + row) * 2] = p0;
          lds_red[(wave * 32 + row) * 2 + 1] = p1;
        }
      }
  }
  __syncthreads();
  if (tid < 64) {
    int row = tid >> 1, o = tid & 1;
    float v = fb[o];
#pragma unroll
    for (int w = 0; w < 4; ++w) v += lds_red[(w * 32 + row) * 2 + o];
    out[(row0 + row) * 2 + o] = v;
  }
}

extern "C" void kernel_launch(void* const* d_in, const int* in_sizes, int n_in,
                              void* d_out, int out_size, void* d_ws, size_t ws_size,
                              hipStream_t stream) {
  const float* x     = (const float*)d_in[0];
  const float* bn0_g = (const float*)d_in[1];
  const float* bn0_b = (const float*)d_in[2];
  const float* bn0_m = (const float*)d_in[3];
  const float* bn0_v = (const float*)d_in[4];
  const float* shW   = (const float*)d_in[5];
  const float* sh_g  = (const float*)d_in[6];
  const float* sh_b  = (const float*)d_in[7];
  const float* sh_m  = (const float*)d_in[8];
  const float* sh_v  = (const float*)d_in[9];
  const float* stW   = (const float*)d_in[10];
  const float* st_g  = (const float*)d_in[11];
  const float* st_b  = (const float*)d_in[12];
  const float* st_m  = (const float*)d_in[13];
  const float* st_v  = (const float*)d_in[14];
  // d_in[15..19] = atW, at_g, at_b, at_m, at_v : dead code (never feeds output)
  const float* fW    = (const float*)d_in[20];
  const float* fb    = (const float*)d_in[21];

  unsigned short* wsu = (unsigned short*)d_ws;
  float* wsf = (float*)d_ws;

  prep_all<<<344, 256, 0, stream>>>(shW, stW, bn0_g, bn0_b, bn0_m, bn0_v, sh_g, sh_b,
                                    sh_m, sh_v, st_g, st_b, st_m, st_v, wsu, wsf);
  tabnet_main<<<4096, 256, 0, stream>>>(x, wsu, wsf, fW, fb, (float*)d_out);
}

// Round 3
// 452.194 us; speedup vs baseline: 1.0939x; 1.0939x over previous
//
#include <hip/hip_runtime.h>

#define EPS 1e-5f

typedef __attribute__((ext_vector_type(8))) short short8;
typedef __attribute__((ext_vector_type(4))) float f32x4;

// ---- ws layout ----
// shorts [0, 131072)      : shW frags, idx = (kq*256 + n)*8 + j, k = kq*8+j (BN0 scale folded)
// shorts [131072, 180224) : stW frags, idx = 131072 + s*16384 + (kq*128 + n')*8 + j,
//                           n = n' (<64) or n'+64
// floats (on d_ws as float*):
#define C1_OFF   90112
#define C2_OFF   90368
#define STC1_OFF 90624
#define STC2_OFF 91392

// HW bf16 conversion path (RNE).
__device__ inline unsigned short f2bf(float f) {
  return __builtin_bit_cast(unsigned short, (__bf16)f);
}

__device__ inline short8 cvt8(f32x4 a, f32x4 b) {
  short8 r;
  r[0] = (short)f2bf(a[0]); r[1] = (short)f2bf(a[1]);
  r[2] = (short)f2bf(a[2]); r[3] = (short)f2bf(a[3]);
  r[4] = (short)f2bf(b[0]); r[5] = (short)f2bf(b[1]);
  r[6] = (short)f2bf(b[2]); r[7] = (short)f2bf(b[3]);
  return r;
}

// async global->LDS, 16B per lane, lane-linear LDS dest (wave-uniform base + lane*16)
__device__ inline void stage16(const float* g, float* l) {
  __builtin_amdgcn_global_load_lds((const __attribute__((address_space(1))) void*)g,
                                   (__attribute__((address_space(3))) void*)l, 16, 0, 0);
}

// ---------------- merged prep kernel ----------------
__global__ void prep_all(const float* __restrict__ shW, const float* __restrict__ stW,
                         const float* __restrict__ bn0_g, const float* __restrict__ bn0_b,
                         const float* __restrict__ bn0_m, const float* __restrict__ bn0_v,
                         const float* __restrict__ sh_g, const float* __restrict__ sh_b,
                         const float* __restrict__ sh_m, const float* __restrict__ sh_v,
                         const float* __restrict__ st_g, const float* __restrict__ st_b,
                         const float* __restrict__ st_m, const float* __restrict__ st_v,
                         unsigned short* __restrict__ ws, float* __restrict__ wsf) {
  if (blockIdx.x < 88) {
    int t = blockIdx.x * 256 + threadIdx.x;
    if (t < 16384) {
      int kq = t >> 8, n = t & 255;
      short8 o;
#pragma unroll
      for (int j = 0; j < 8; ++j) {
        int k = kq * 8 + j;
        float scale = bn0_g[k] * rsqrtf(bn0_v[k] + EPS);
        o[j] = (short)f2bf(shW[k * 256 + n] * scale);
      }
      *(short8*)&ws[t * 8] = o;
    } else if (t < 16384 + 6144) {
      int r = t - 16384;
      int s = r >> 11, rem = r & 2047;
      int kq = rem >> 7, np = rem & 127;
      int n = np < 64 ? np : np + 64;
      short8 o;
#pragma unroll
      for (int j = 0; j < 8; ++j) o[j] = (short)f2bf(stW[(s * 128 + kq * 8 + j) * 256 + n]);
      *(short8*)&ws[131072 + r * 8] = o;
    }
    return;
  }

  const int n = blockIdx.x - 88, t = threadIdx.x;
  float part = 0.f;
#pragma unroll
  for (int kk = 0; kk < 2; ++kk) {
    int k = t + kk * 256;
    float sc = bn0_g[k] * rsqrtf(bn0_v[k] + EPS);
    part += (bn0_b[k] - bn0_m[k] * sc) * shW[k * 256 + n];
  }
#pragma unroll
  for (int m = 1; m < 64; m <<= 1) part += __shfl_xor(part, m);
  __shared__ float wsum[4];
  if ((t & 63) == 0) wsum[t >> 6] = part;
  __syncthreads();
  if (t == 0) {
    float bias = wsum[0] + wsum[1] + wsum[2] + wsum[3];
    float c1 = sh_g[n] * rsqrtf(sh_v[n] + EPS);
    wsf[C1_OFF + n] = c1;
    wsf[C2_OFF + n] = (bias - sh_m[n]) * c1 + sh_b[n];
#pragma unroll
    for (int s = 0; s < 3; ++s) {
      float a = st_g[s * 256 + n] * rsqrtf(st_v[s * 256 + n] + EPS);
      wsf[STC1_OFF + s * 256 + n] = a;
      wsf[STC2_OFF + s * 256 + n] = st_b[s * 256 + n] - st_m[s * 256 + n] * a;
    }
  }
}

// ---------------- main fused kernel ----------------
// 4096 blocks x 256 threads, 32 rows/block. Phase 1: x staged once per block
// into double-buffered LDS via global_load_lds (16B lanes), 8 chunks of 64
// cols, XOR-swizzled (source-side AND read-side, rule 21) to kill the 16-way
// ds_read bank conflict of a 256B-stride tile. B loads issued BEFORE the stage
// issue so the MFMA B-wait is vmcnt(2) and the staged loads stay in flight
// across the chunk. One barrier per chunk.
__global__ __launch_bounds__(256, 4) void tabnet_main(
    const float* __restrict__ x, const unsigned short* __restrict__ wsu,
    const float* __restrict__ wsf, const float* __restrict__ fW,
    const float* __restrict__ fb, float* __restrict__ out) {

  __shared__ __align__(16) float xbuf[2][32 * 64];              // 2 x 8 KB, x chunk dbuf
  __shared__ __align__(16) unsigned short lds_sh[16 * 32 * 8];  // 8 KB, sh A-frags
  __shared__ float lds_red[4 * 32 * 2];                         // 1 KB

  const int tid = threadIdx.x;
  const int wave = tid >> 6, lane = tid & 63;
  const int q = lane >> 4, l15 = lane & 15;
  const int l7 = l15 & 7;
  const long row0 = (long)blockIdx.x * 32;

  // B column per nt: nt 0,1 = value cols, nt 2,3 = gate cols (+128)
  int ncol[4];
#pragma unroll
  for (int nt = 0; nt < 4; ++nt)
    ncol[nt] = wave * 32 + (nt & 1) * 16 + (nt >> 1) * 128 + l15;

  // ---- staging addresses: wave w stages rows w*8 .. w*8+7 (2 instrs x 4 rows) ----
  // LDS linear: row-major [32][64] f32. Source col pre-swizzled: LDS(row, slot16)
  // holds X(row, slot16 ^ (row&7)) [units of 16B]; read applies the same XOR.
  const int sr = lane >> 4;   // sub-row 0..3 within a 4-row staging instr
  const int sl = lane & 15;   // 16B slot 0..15 within the 64-float row
  const float* gsrc[2];
  float* ldst[2];
#pragma unroll
  for (int j = 0; j < 2; ++j) {
    int rj = wave * 8 + j * 4 + sr;                 // row within block (0..31)
    int colf = (sl ^ ((rj & 7))) * 4;               // swizzled col in floats
    gsrc[j] = x + (row0 + rj) * 512 + colf;
    ldst[j] = &xbuf[0][(wave * 8 + j * 4) * 64];    // wave-uniform base (lane*16 auto)
  }

  f32x4 acc[2][4];
#pragma unroll
  for (int a = 0; a < 2; ++a)
#pragma unroll
    for (int b = 0; b < 4; ++b) acc[a][b] = (f32x4)0.f;

  // prologue: stage chunk 0 into buf 0
#pragma unroll
  for (int j = 0; j < 2; ++j) stage16(gsrc[j], ldst[j]);
  __syncthreads();

  // ---- Phase 1: 8 chunks x (2 k-steps of K=32) ----
  for (int chunk = 0; chunk < 8; ++chunk) {
    const int b = chunk & 1;
    // B loads for both k-steps FIRST (older than the stage issue below ->
    // MFMA waits vmcnt(2), stage stays in flight)
    short8 bs[2][4];
#pragma unroll
    for (int ks = 0; ks < 2; ++ks)
#pragma unroll
      for (int nt = 0; nt < 4; ++nt)
        bs[ks][nt] = *(const short8*)&wsu[(((chunk * 2 + ks) * 4 + q) * 256 + ncol[nt]) * 8];
    // issue next chunk's stage into the other buffer
    if (chunk < 7) {
#pragma unroll
      for (int j = 0; j < 2; ++j)
        stage16(gsrc[j] + (chunk + 1) * 64, &ldst[j][(b ^ 1) * 32 * 64]);
    }
    // compute this chunk from LDS
#pragma unroll
    for (int ks = 0; ks < 2; ++ks) {
      short8 af[2];
#pragma unroll
      for (int mt = 0; mt < 2; ++mt) {
        const float* xr = &xbuf[b][(16 * mt + l15) * 64];
        int o0 = ((ks * 8 + q * 2) ^ l7) * 4;
        int o1 = ((ks * 8 + q * 2 + 1) ^ l7) * 4;
        f32x4 lo = *(const f32x4*)(xr + o0);
        f32x4 hi = *(const f32x4*)(xr + o1);
        af[mt] = cvt8(lo, hi);
      }
#pragma unroll
      for (int nt = 0; nt < 4; ++nt)
#pragma unroll
        for (int mt = 0; mt < 2; ++mt)
          acc[mt][nt] =
              __builtin_amdgcn_mfma_f32_16x16x32_bf16(af[mt], bs[ks][nt], acc[mt][nt], 0, 0, 0);
    }
    __syncthreads();  // drains stage (vmcnt 0) + publishes buf for next chunk
  }

  // ---- Phase-1 epilogue: BN + GLU in registers -> lds_sh (A-frag layout) ----
#pragma unroll
  for (int nt = 0; nt < 2; ++nt) {
    const int c = wave * 32 + nt * 16 + l15;
    const float v1 = wsf[C1_OFF + c], v2 = wsf[C2_OFF + c];
    const float g1 = wsf[C1_OFF + c + 128], g2 = wsf[C2_OFF + c + 128];
#pragma unroll
    for (int mt = 0; mt < 2; ++mt)
#pragma unroll
      for (int r = 0; r < 4; ++r) {
        float y1 = acc[mt][nt][r] * v1 + v2;
        float y2 = acc[mt][nt + 2][r] * g1 + g2;
        float sg = __builtin_amdgcn_rcpf(1.f + __expf(-y2));
        int row = 16 * mt + 4 * q + r;
        lds_sh[((c >> 3) * 32 + row) * 8 + (c & 7)] = f2bf(y1 * sg);
      }
  }
  __syncthreads();

  // ---- Phase 2: 3 steps, K=128; A from lds_sh, B direct from global; GLU in regs ----
  float agg[8];
#pragma unroll
  for (int i = 0; i < 8; ++i) agg[i] = 0.f;

  for (int s = 0; s < 3; ++s) {
    const unsigned short* wb = wsu + 131072 + s * 16384;
    short8 bsx[4][2];
#pragma unroll
    for (int ks = 0; ks < 4; ++ks) {
      int kq = ks * 4 + q;
      bsx[ks][0] = *(const short8*)&wb[(kq * 128 + wave * 16 + l15) * 8];
      bsx[ks][1] = *(const short8*)&wb[(kq * 128 + 64 + wave * 16 + l15) * 8];
    }
    f32x4 acc2[2][2];
#pragma unroll
    for (int a = 0; a < 2; ++a)
#pragma unroll
      for (int b = 0; b < 2; ++b) acc2[a][b] = (f32x4)0.f;
#pragma unroll
    for (int ks = 0; ks < 4; ++ks) {
      int kq = ks * 4 + q;
      short8 af[2];
#pragma unroll
      for (int mt = 0; mt < 2; ++mt)
        af[mt] = *(const short8*)&lds_sh[(kq * 32 + 16 * mt + l15) * 8];
#pragma unroll
      for (int nt = 0; nt < 2; ++nt)
#pragma unroll
        for (int mt = 0; mt < 2; ++mt)
          acc2[mt][nt] =
              __builtin_amdgcn_mfma_f32_16x16x32_bf16(af[mt], bsx[ks][nt], acc2[mt][nt], 0, 0, 0);
    }
    const int n1 = wave * 16 + l15, n2 = 128 + wave * 16 + l15;
    const float a1 = wsf[STC1_OFF + s * 256 + n1], b1 = wsf[STC2_OFF + s * 256 + n1];
    const float a2 = wsf[STC1_OFF + s * 256 + n2], b2 = wsf[STC2_OFF + s * 256 + n2];
#pragma unroll
    for (int mt = 0; mt < 2; ++mt)
#pragma unroll
      for (int r = 0; r < 4; ++r) {
        float y1 = acc2[mt][0][r] * a1 + b1;
        float y2 = acc2[mt][1][r] * a2 + b2;
        agg[mt * 4 + r] += y1 * __builtin_amdgcn_rcpf(1.f + __expf(-y2));
      }
  }

  // ---- Final: out = agg @ fW + fb (shfl reduce over the 16 cols per wave) ----
  {
    const int c = wave * 16 + l15;
    const float w0 = fW[c * 2], w1 = fW[c * 2 + 1];
#pragma unroll
    for (int mt = 0; mt < 2; ++mt)
#pragma unroll
      for (int r = 0; r < 4; ++r) {
        float p0 = agg[mt * 4 + r] * w0;
        float p1 = agg[mt * 4 + r] * w1;
#pragma unroll
        for (int m = 1; m < 16; m <<= 1) {
          p0 += __shfl_xor(p0, m);
          p1 += __shfl_xor(p1, m);
        }
        if (l15 == 0) {
          int row = 16 * mt + 4 * q + r;
          lds_red[(wave * 32 + row) * 2] = p0;
          lds_red[(wave * 32 + row) * 2 + 1] = p1;
        }
      }
  }
  __syncthreads();
  if (tid < 64) {
    int row = tid >> 1, o = tid & 1;
    float v = fb[o];
#pragma unroll
    for (int w = 0; w < 4; ++w) v += lds_red[(w * 32 + row) * 2 + o];
    out[(row0 + row) * 2 + o] = v;
  }
}

extern "C" void kernel_launch(void* const* d_in, const int* in_sizes, int n_in,
                              void* d_out, int out_size, void* d_ws, size_t ws_size,
                              hipStream_t stream) {
  const float* x     = (const float*)d_in[0];
  const float* bn0_g = (const float*)d_in[1];
  const float* bn0_b = (const float*)d_in[2];
  const float* bn0_m = (const float*)d_in[3];
  const float* bn0_v = (const float*)d_in[4];
  const float* shW   = (const float*)d_in[5];
  const float* sh_g  = (const float*)d_in[6];
  const float* sh_b  = (const float*)d_in[7];
  const float* sh_m  = (const float*)d_in[8];
  const float* sh_v  = (const float*)d_in[9];
  const float* stW   = (const float*)d_in[10];
  const float* st_g  = (const float*)d_in[11];
  const float* st_b  = (const float*)d_in[12];
  const float* st_m  = (const float*)d_in[13];
  const float* st_v  = (const float*)d_in[14];
  // d_in[15..19] = atW, at_g, at_b, at_m, at_v : dead code (never feeds output)
  const float* fW    = (const float*)d_in[20];
  const float* fb    = (const float*)d_in[21];

  unsigned short* wsu = (unsigned short*)d_ws;
  float* wsf = (float*)d_ws;

  prep_all<<<344, 256, 0, stream>>>(shW, stW, bn0_g, bn0_b, bn0_m, bn0_v, sh_g, sh_b,
                                    sh_m, sh_v, st_g, st_b, st_m, st_v, wsu, wsf);
  tabnet_main<<<4096, 256, 0, stream>>>(x, wsu, wsf, fW, fb, (float*)d_out);
}

// Round 5
// 437.821 us; speedup vs baseline: 1.1298x; 1.0328x over previous
//
#include <hip/hip_runtime.h>

#define EPS 1e-5f

typedef __attribute__((ext_vector_type(8))) short short8;
typedef __attribute__((ext_vector_type(4))) float f32x4;

// ---- ws layout ----
// shorts [0, 131072)      : shW frags, idx = (kq*256 + n)*8 + j, k = kq*8+j (BN0 scale folded)
// shorts [131072, 180224) : stW frags, idx = 131072 + s*16384 + (kq*128 + n')*8 + j,
//                           n = n' (<64) or n'+64
// floats (on d_ws as float*):
#define C1_OFF   90112
#define C2_OFF   90368
#define STC1_OFF 90624
#define STC2_OFF 91392

// zero-cost compiler fence: pins VMEM issue order (memory clobber blocks both
// load hoisting and global_load_lds reordering across it, at IR and MIR level)
#define VMEM_FENCE() asm volatile("" ::: "memory")

// HW bf16 conversion path (RNE).
__device__ inline unsigned short f2bf(float f) {
  return __builtin_bit_cast(unsigned short, (__bf16)f);
}

__device__ inline short8 cvt8(f32x4 a, f32x4 b) {
  short8 r;
  r[0] = (short)f2bf(a[0]); r[1] = (short)f2bf(a[1]);
  r[2] = (short)f2bf(a[2]); r[3] = (short)f2bf(a[3]);
  r[4] = (short)f2bf(b[0]); r[5] = (short)f2bf(b[1]);
  r[6] = (short)f2bf(b[2]); r[7] = (short)f2bf(b[3]);
  return r;
}

// async global->LDS, 16B per lane, lane-linear LDS dest (wave-uniform base + lane*16)
__device__ inline void stage16(const float* g, float* l) {
  __builtin_amdgcn_global_load_lds((const __attribute__((address_space(1))) void*)g,
                                   (__attribute__((address_space(3))) void*)l, 16, 0, 0);
}

// ---------------- merged prep kernel ----------------
__global__ void prep_all(const float* __restrict__ shW, const float* __restrict__ stW,
                         const float* __restrict__ bn0_g, const float* __restrict__ bn0_b,
                         const float* __restrict__ bn0_m, const float* __restrict__ bn0_v,
                         const float* __restrict__ sh_g, const float* __restrict__ sh_b,
                         const float* __restrict__ sh_m, const float* __restrict__ sh_v,
                         const float* __restrict__ st_g, const float* __restrict__ st_b,
                         const float* __restrict__ st_m, const float* __restrict__ st_v,
                         unsigned short* __restrict__ ws, float* __restrict__ wsf) {
  if (blockIdx.x < 88) {
    int t = blockIdx.x * 256 + threadIdx.x;
    if (t < 16384) {
      int kq = t >> 8, n = t & 255;
      short8 o;
#pragma unroll
      for (int j = 0; j < 8; ++j) {
        int k = kq * 8 + j;
        float scale = bn0_g[k] * rsqrtf(bn0_v[k] + EPS);
        o[j] = (short)f2bf(shW[k * 256 + n] * scale);
      }
      *(short8*)&ws[t * 8] = o;
    } else if (t < 16384 + 6144) {
      int r = t - 16384;
      int s = r >> 11, rem = r & 2047;
      int kq = rem >> 7, np = rem & 127;
      int n = np < 64 ? np : np + 64;
      short8 o;
#pragma unroll
      for (int j = 0; j < 8; ++j) o[j] = (short)f2bf(stW[(s * 128 + kq * 8 + j) * 256 + n]);
      *(short8*)&ws[131072 + r * 8] = o;
    }
    return;
  }

  const int n = blockIdx.x - 88, t = threadIdx.x;
  float part = 0.f;
#pragma unroll
  for (int kk = 0; kk < 2; ++kk) {
    int k = t + kk * 256;
    float sc = bn0_g[k] * rsqrtf(bn0_v[k] + EPS);
    part += (bn0_b[k] - bn0_m[k] * sc) * shW[k * 256 + n];
  }
#pragma unroll
  for (int m = 1; m < 64; m <<= 1) part += __shfl_xor(part, m);
  __shared__ float wsum[4];
  if ((t & 63) == 0) wsum[t >> 6] = part;
  __syncthreads();
  if (t == 0) {
    float bias = wsum[0] + wsum[1] + wsum[2] + wsum[3];
    float c1 = sh_g[n] * rsqrtf(sh_v[n] + EPS);
    wsf[C1_OFF + n] = c1;
    wsf[C2_OFF + n] = (bias - sh_m[n]) * c1 + sh_b[n];
#pragma unroll
    for (int s = 0; s < 3; ++s) {
      float a = st_g[s * 256 + n] * rsqrtf(st_v[s * 256 + n] + EPS);
      wsf[STC1_OFF + s * 256 + n] = a;
      wsf[STC2_OFF + s * 256 + n] = st_b[s * 256 + n] - st_m[s * 256 + n] * a;
    }
  }
}

// ---------------- main fused kernel ----------------
// 4096 blocks x 256 threads, 32 rows/block. Phase 1: x staged into 3-buffer
// LDS ring via global_load_lds, issued 2 chunks ahead; B-frags double-buffered
// in registers, issued 1 chunk ahead. All VMEM issue order is PINNED with
// zero-cost compiler fences so the counted vmcnt waits are order-invariant:
// at top of chunk c the outstanding set is at most {stage(c)x2 (oldest),
// B(c)x8, stage(c+1)x2} -> vmcnt(10) always completes exactly stage(c).
// No vmcnt(0) drain anywhere in the main loop (R4's failure was this count
// without pinned order: LLVM hoisted B(0) above the prologue stages).
__global__ __launch_bounds__(256, 4) void tabnet_main(
    const float* __restrict__ x, const unsigned short* __restrict__ wsu,
    const float* __restrict__ wsf, const float* __restrict__ fW,
    const float* __restrict__ fb, float* __restrict__ out) {

  __shared__ __align__(16) float xbuf[3][32 * 64];              // 3 x 8 KB, x chunk ring
  __shared__ __align__(16) unsigned short lds_sh[16 * 32 * 8];  // 8 KB, sh A-frags
  __shared__ float lds_red[4 * 32 * 2];                         // 1 KB

  const int tid = threadIdx.x;
  const int wave = tid >> 6, lane = tid & 63;
  const int q = lane >> 4, l15 = lane & 15;
  const int l7 = l15 & 7;
  const long row0 = (long)blockIdx.x * 32;

  // B column per nt: nt 0,1 = value cols, nt 2,3 = gate cols (+128)
  int ncol[4];
#pragma unroll
  for (int nt = 0; nt < 4; ++nt)
    ncol[nt] = wave * 32 + (nt & 1) * 16 + (nt >> 1) * 128 + l15;

  // ---- staging addresses: wave w stages rows w*8 .. w*8+7 (2 instrs x 4 rows) ----
  // LDS linear row-major [32][64] f32. Source col pre-swizzled: LDS(row, slot16)
  // holds X(row, slot16 ^ (row&7)) [16B units]; read applies the same XOR.
  const int sr = lane >> 4;   // sub-row 0..3 within a 4-row staging instr
  const int sl = lane & 15;   // 16B slot 0..15 within the 64-float row
  const float* gsrc[2];
  float* ldst[2];
#pragma unroll
  for (int j = 0; j < 2; ++j) {
    int rj = wave * 8 + j * 4 + sr;                 // row within block (0..31)
    int colf = (sl ^ ((rj & 7))) * 4;               // swizzled col in floats
    gsrc[j] = x + (row0 + rj) * 512 + colf;
    ldst[j] = &xbuf[0][(wave * 8 + j * 4) * 64];    // wave-uniform base (lane*16 auto)
  }

  f32x4 acc[2][4];
#pragma unroll
  for (int a = 0; a < 2; ++a)
#pragma unroll
    for (int b = 0; b < 4; ++b) acc[a][b] = (f32x4)0.f;

  short8 bs[2][2][4];  // [chunk parity][kstep][nt], statically indexed (full unroll)

  // ---- prologue: stage chunks 0,1 (in order), then B(0) — order pinned ----
#pragma unroll
  for (int j = 0; j < 2; ++j) stage16(gsrc[j], ldst[j]);
#pragma unroll
  for (int j = 0; j < 2; ++j) stage16(gsrc[j] + 64, &ldst[j][32 * 64]);
  VMEM_FENCE();
#pragma unroll
  for (int ks = 0; ks < 2; ++ks)
#pragma unroll
    for (int nt = 0; nt < 4; ++nt)
      bs[0][ks][nt] = *(const short8*)&wsu[((ks * 4 + q) * 256 + ncol[nt]) * 8];
  VMEM_FENCE();

  // ---- Phase 1: 8 chunks x (2 k-steps of K=32), counted-vmcnt pipeline ----
#pragma unroll
  for (int chunk = 0; chunk < 8; ++chunk) {
    const int b = chunk % 3;
    // top wait: completes stage(chunk). Outstanding here (issue-order FIFO,
    // pinned): stage(chunk)x2 [oldest], B(chunk)x8, stage(chunk+1)x2 = <=12.
    // vmcnt(10) retires the 2 oldest = stage(chunk). Chunk 7 has no
    // stage(8) -> <=10 outstanding -> vmcnt(8).
    if (chunk < 7)
      asm volatile("s_waitcnt vmcnt(10)" ::: "memory");
    else
      asm volatile("s_waitcnt vmcnt(8)" ::: "memory");
    __builtin_amdgcn_s_barrier();   // publish all waves' stage(chunk); no drain
    // stage(chunk+2): buffer (chunk+2)%3 was last read in chunk-1; every wave
    // crossed the barrier above, so its reads are done -> WAR-safe.
    if (chunk < 6) {
#pragma unroll
      for (int j = 0; j < 2; ++j)
        stage16(gsrc[j] + (chunk + 2) * 64, &ldst[j][((chunk + 2) % 3) * 32 * 64]);
    }
    VMEM_FENCE();
    // prefetch next chunk's B into the other parity (1 chunk of latency hiding;
    // compiler's pre-MFMA wait for B(chunk) is vmcnt(10) = leaves these +
    // stage(chunk+2) in flight)
    if (chunk < 7) {
#pragma unroll
      for (int ks = 0; ks < 2; ++ks)
#pragma unroll
        for (int nt = 0; nt < 4; ++nt)
          bs[(chunk + 1) & 1][ks][nt] =
              *(const short8*)&wsu[((((chunk + 1) * 2 + ks) * 4 + q) * 256 + ncol[nt]) * 8];
    }
    VMEM_FENCE();
    // compute this chunk from LDS (ds_reads can't hoist above the fences/asm)
#pragma unroll
    for (int ks = 0; ks < 2; ++ks) {
      short8 af[2];
#pragma unroll
      for (int mt = 0; mt < 2; ++mt) {
        const float* xr = &xbuf[b][(16 * mt + l15) * 64];
        int o0 = ((ks * 8 + q * 2) ^ l7) * 4;
        int o1 = ((ks * 8 + q * 2 + 1) ^ l7) * 4;
        f32x4 lo = *(const f32x4*)(xr + o0);
        f32x4 hi = *(const f32x4*)(xr + o1);
        af[mt] = cvt8(lo, hi);
      }
#pragma unroll
      for (int nt = 0; nt < 4; ++nt)
#pragma unroll
        for (int mt = 0; mt < 2; ++mt)
          acc[mt][nt] = __builtin_amdgcn_mfma_f32_16x16x32_bf16(af[mt], bs[chunk & 1][ks][nt],
                                                                acc[mt][nt], 0, 0, 0);
    }
  }

  // ---- Phase-1 epilogue: BN + GLU in registers -> lds_sh (A-frag layout) ----
#pragma unroll
  for (int nt = 0; nt < 2; ++nt) {
    const int c = wave * 32 + nt * 16 + l15;
    const float v1 = wsf[C1_OFF + c], v2 = wsf[C2_OFF + c];
    const float g1 = wsf[C1_OFF + c + 128], g2 = wsf[C2_OFF + c + 128];
#pragma unroll
    for (int mt = 0; mt < 2; ++mt)
#pragma unroll
      for (int r = 0; r < 4; ++r) {
        float y1 = acc[mt][nt][r] * v1 + v2;
        float y2 = acc[mt][nt + 2][r] * g1 + g2;
        float sg = __builtin_amdgcn_rcpf(1.f + __expf(-y2));
        int row = 16 * mt + 4 * q + r;
        lds_sh[((c >> 3) * 32 + row) * 8 + (c & 7)] = f2bf(y1 * sg);
      }
  }
  __syncthreads();

  // ---- Phase 2: 3 steps, K=128; A from lds_sh, B direct from global; GLU in regs ----
  float agg[8];
#pragma unroll
  for (int i = 0; i < 8; ++i) agg[i] = 0.f;

  for (int s = 0; s < 3; ++s) {
    const unsigned short* wb = wsu + 131072 + s * 16384;
    short8 bsx[4][2];
#pragma unroll
    for (int ks = 0; ks < 4; ++ks) {
      int kq = ks * 4 + q;
      bsx[ks][0] = *(const short8*)&wb[(kq * 128 + wave * 16 + l15) * 8];
      bsx[ks][1] = *(const short8*)&wb[(kq * 128 + 64 + wave * 16 + l15) * 8];
    }
    f32x4 acc2[2][2];
#pragma unroll
    for (int a = 0; a < 2; ++a)
#pragma unroll
      for (int b = 0; b < 2; ++b) acc2[a][b] = (f32x4)0.f;
#pragma unroll
    for (int ks = 0; ks < 4; ++ks) {
      int kq = ks * 4 + q;
      short8 af[2];
#pragma unroll
      for (int mt = 0; mt < 2; ++mt)
        af[mt] = *(const short8*)&lds_sh[(kq * 32 + 16 * mt + l15) * 8];
#pragma unroll
      for (int nt = 0; nt < 2; ++nt)
#pragma unroll
        for (int mt = 0; mt < 2; ++mt)
          acc2[mt][nt] =
              __builtin_amdgcn_mfma_f32_16x16x32_bf16(af[mt], bsx[ks][nt], acc2[mt][nt], 0, 0, 0);
    }
    const int n1 = wave * 16 + l15, n2 = 128 + wave * 16 + l15;
    const float a1 = wsf[STC1_OFF + s * 256 + n1], b1 = wsf[STC2_OFF + s * 256 + n1];
    const float a2 = wsf[STC1_OFF + s * 256 + n2], b2 = wsf[STC2_OFF + s * 256 + n2];
#pragma unroll
    for (int mt = 0; mt < 2; ++mt)
#pragma unroll
      for (int r = 0; r < 4; ++r) {
        float y1 = acc2[mt][0][r] * a1 + b1;
        float y2 = acc2[mt][1][r] * a2 + b2;
        agg[mt * 4 + r] += y1 * __builtin_amdgcn_rcpf(1.f + __expf(-y2));
      }
  }

  // ---- Final: out = agg @ fW + fb (shfl reduce over the 16 cols per wave) ----
  {
    const int c = wave * 16 + l15;
    const float w0 = fW[c * 2], w1 = fW[c * 2 + 1];
#pragma unroll
    for (int mt = 0; mt < 2; ++mt)
#pragma unroll
      for (int r = 0; r < 4; ++r) {
        float p0 = agg[mt * 4 + r] * w0;
        float p1 = agg[mt * 4 + r] * w1;
#pragma unroll
        for (int m = 1; m < 16; m <<= 1) {
          p0 += __shfl_xor(p0, m);
          p1 += __shfl_xor(p1, m);
        }
        if (l15 == 0) {
          int row = 16 * mt + 4 * q + r;
          lds_red[(wave * 32 + row) * 2] = p0;
          lds_red[(wave * 32 + row) * 2 + 1] = p1;
        }
      }
  }
  __syncthreads();
  if (tid < 64) {
    int row = tid >> 1, o = tid & 1;
    float v = fb[o];
#pragma unroll
    for (int w = 0; w < 4; ++w) v += lds_red[(w * 32 + row) * 2 + o];
    out[(row0 + row) * 2 + o] = v;
  }
}

extern "C" void kernel_launch(void* const* d_in, const int* in_sizes, int n_in,
                              void* d_out, int out_size, void* d_ws, size_t ws_size,
                              hipStream_t stream) {
  const float* x     = (const float*)d_in[0];
  const float* bn0_g = (const float*)d_in[1];
  const float* bn0_b = (const float*)d_in[2];
  const float* bn0_m = (const float*)d_in[3];
  const float* bn0_v = (const float*)d_in[4];
  const float* shW   = (const float*)d_in[5];
  const float* sh_g  = (const float*)d_in[6];
  const float* sh_b  = (const float*)d_in[7];
  const float* sh_m  = (const float*)d_in[8];
  const float* sh_v  = (const float*)d_in[9];
  const float* stW   = (const float*)d_in[10];
  const float* st_g  = (const float*)d_in[11];
  const float* st_b  = (const float*)d_in[12];
  const float* st_m  = (const float*)d_in[13];
  const float* st_v  = (const float*)d_in[14];
  // d_in[15..19] = atW, at_g, at_b, at_m, at_v : dead code (never feeds output)
  const float* fW    = (const float*)d_in[20];
  const float* fb    = (const float*)d_in[21];

  unsigned short* wsu = (unsigned short*)d_ws;
  float* wsf = (float*)d_ws;

  prep_all<<<344, 256, 0, stream>>>(shW, stW, bn0_g, bn0_b, bn0_m, bn0_v, sh_g, sh_b,
                                    sh_m, sh_v, st_g, st_b, st_m, st_v, wsu, wsf);
  tabnet_main<<<4096, 256, 0, stream>>>(x, wsu, wsf, fW, fb, (float*)d_out);
}